// Round 17
// baseline (1334.482 us; speedup 1.0000x reference)
//
#include <hip/hip_runtime.h>

#define TT  64
#define BSZ 512
#define ISZ 512
#define HSZ 1024

typedef short bf16x8 __attribute__((ext_vector_type(8)));
typedef float f32x4 __attribute__((ext_vector_type(4)));
typedef unsigned short u16x8 __attribute__((ext_vector_type(8)));

typedef const __attribute__((address_space(1))) unsigned int* gas_t;
typedef __attribute__((address_space(3))) unsigned int* las_t;

__device__ __forceinline__ unsigned short f2bf(float f) {
    unsigned int u = __float_as_uint(f);
    unsigned int r = u + 0x7FFFu + ((u >> 16) & 1u);   // RNE
    return (unsigned short)(r >> 16);
}

__global__ void cast_f32_to_bf16(const float* __restrict__ in,
                                 unsigned short* __restrict__ out, int n8) {
    int i = blockIdx.x * blockDim.x + threadIdx.x;
    if (i >= n8) return;
    const float4* p = (const float4*)(in + (size_t)i * 8);
    float4 v0 = p[0], v1 = p[1];
    u16x8 o;
    o[0] = f2bf(v0.x); o[1] = f2bf(v0.y); o[2] = f2bf(v0.z); o[3] = f2bf(v0.w);
    o[4] = f2bf(v1.x); o[5] = f2bf(v1.y); o[6] = f2bf(v1.z); o[7] = f2bf(v1.w);
    *(u16x8*)(out + (size_t)i * 8) = o;
}

__global__ void bias_combine(const float* __restrict__ a,
                             const float* __restrict__ b,
                             float* __restrict__ o) {
    int i = blockIdx.x * blockDim.x + threadIdx.x;
    if (i < 4 * HSZ) o[i] = a[i] + b[i];
}

// ---------------- One launch per step; x-projection FUSED -------------------
// 256 blocks (1/CU via 144KB LDS), 512 thr = 8 waves. mi=bid>>6, ni=bid&63.
// Per step, per wave (mg = wv&3 rows, ks = wv>>2 K-half):
//   gates = bias (ks0) + x_t[.,ks*256:+256] @ Wih^T + h_{t-1}[.,ks*512:+512] @ Whh^T
// W_hh slice -> LDS (L2-warm after first steps). W_ih/x fragments direct
// from global (per-XCD working set: 512KB Wih + 0.5MB x, L2-resident).
// Pinned issue order: bias+c | W(16) | ax(16) | a0(16) -> vmcnt(32), barrier
// -> vmcnt(16) -> x-MFMA loop -> a1(16) -> MFMA b0 -> vmcnt(0) -> MFMA b1
// -> ks exchange -> fused LSTM epilogue. No XG intermediate at all.
__global__ __launch_bounds__(512, 2) void lstm_step(
    const unsigned short* __restrict__ xb,    // [TT,512,512] bf16
    const unsigned short* __restrict__ Wihb,  // [4096,512] bf16
    const unsigned short* __restrict__ Whhb,  // [4096,1024] bf16
    const float* __restrict__ bias,           // [4096]
    const unsigned short* __restrict__ hprev, // [64][512][16] bf16
    unsigned short* __restrict__ hnext,       // [64][512][16] bf16
    float* __restrict__ cst,                  // [4*64*512][4] fp32
    float* __restrict__ out,
    int t)
{
    __shared__ unsigned short WhL[64 * 1024];   // 128 KiB W_hh slice
    __shared__ float WS[4096];                  //  16 KiB ks exchange

    const int tid  = threadIdx.x;
    const int lane = tid & 63;
    const int wv   = tid >> 6;
    const int mg   = wv & 3;
    const int ks   = wv >> 2;
    const int lr   = lane & 15;
    const int kq   = lane >> 4;
    const int mi   = blockIdx.x >> 6;
    const int ni   = blockIdx.x & 63;
    const int b0   = mi * 128;
    const int hc0  = ni * 16;

    const int bth = b0 + mg * 32 + ks * 16 + kq * 4;   // this thread's 4 rows
    const int n   = hc0 + lr;
    float* cth = cst + (((size_t)mi * 64 + ni) * 512 + tid) * 4;

    // x / W_ih fragment pointers (K-half ks)
    const unsigned short* xr = xb + (size_t)t * BSZ * ISZ
                             + (size_t)(b0 + mg * 32 + lr) * ISZ + ks * 256 + kq * 8;
    const unsigned short* wih_p = Wihb + (size_t)(hc0 + lr) * ISZ + ks * 256 + kq * 8;

    f32x4 accf[4];
    f32x4 cr;

    if (t > 0) {
        // ---- group 0: bias + c (oldest -> their use never drains others) ----
        float bv[4];
        #pragma unroll
        for (int g = 0; g < 4; ++g) bv[g] = bias[g * HSZ + n];
        cr = *(const f32x4*)(cth);
        __builtin_amdgcn_sched_barrier(0);

        // ---- group 1: W_hh stage (16 gload_lds) ----
        #pragma unroll
        for (int i = 0; i < 16; ++i) {
            const int li = wv * 16 + i;
            const int r = li >> 1, half = li & 1;
            const int grow = (r >> 4) * HSZ + hc0 + (r & 15);
            const int gslot = (half * 64 + lane) ^ (r & 7);
            const unsigned short* g = Whhb + (size_t)grow * HSZ + (size_t)gslot * 8;
            __builtin_amdgcn_global_load_lds((gas_t)g, (las_t)(WhL + li * 512), 16, 0, 0);
        }
        __builtin_amdgcn_sched_barrier(0);

        // ---- group 2: x fragments (16 loads) ----
        bf16x8 ax[2][8];
        #pragma unroll
        for (int j = 0; j < 8; ++j) {
            ax[0][j] = *(const bf16x8*)(xr + j * 32);
            ax[1][j] = *(const bf16x8*)(xr + 16 * ISZ + j * 32);
        }
        __builtin_amdgcn_sched_barrier(0);

        // ---- group 3: h batch 0 (16 loads) ----
        const int br0 = b0 + mg * 32 + lr;
        bf16x8 a0[2][8];
        #pragma unroll
        for (int c = 0; c < 8; ++c) {
            const int kc = ks * 512 + c * 32 + kq * 8;
            const size_t base = (size_t)(kc >> 4) * 8192 + (kc & 15);
            a0[0][c] = *(const bf16x8*)(hprev + base + (size_t)br0 * 16);
            a0[1][c] = *(const bf16x8*)(hprev + base + (size_t)(br0 + 16) * 16);
        }
        __builtin_amdgcn_sched_barrier(0);

        // ---- own W writes done (younger: ax16 + a0 16 = 32) ----
        asm volatile("s_waitcnt vmcnt(32)" ::: "memory");
        __builtin_amdgcn_sched_barrier(0);
        __builtin_amdgcn_s_barrier();       // all waves' W writes visible

        // ---- x fragments ready (younger: a0 16) ----
        asm volatile("s_waitcnt vmcnt(16)" ::: "memory");
        __builtin_amdgcn_sched_barrier(0);

        f32x4 acc[2][4];
        #pragma unroll
        for (int m = 0; m < 2; ++m)
            #pragma unroll
            for (int g = 0; g < 4; ++g)
                acc[m][g] = (ks == 0) ? (f32x4){bv[g], bv[g], bv[g], bv[g]}
                                      : (f32x4){0.f, 0.f, 0.f, 0.f};

        // ---- x-projection MFMAs (W_ih frags L2-hot, compiler-scheduled) ----
        #pragma unroll
        for (int j = 0; j < 8; ++j) {
            #pragma unroll
            for (int g = 0; g < 4; ++g) {
                bf16x8 wf = *(const bf16x8*)(wih_p + (size_t)g * (HSZ * ISZ) + j * 32);
                acc[0][g] = __builtin_amdgcn_mfma_f32_16x16x32_bf16(ax[0][j], wf, acc[0][g], 0, 0, 0);
                acc[1][g] = __builtin_amdgcn_mfma_f32_16x16x32_bf16(ax[1][j], wf, acc[1][g], 0, 0, 0);
            }
        }
        __builtin_amdgcn_sched_barrier(0);

        // ---- h batch 1 (16 loads; overlap with b0 MFMAs) ----
        bf16x8 a1[2][8];
        #pragma unroll
        for (int c = 0; c < 8; ++c) {
            const int kc = ks * 512 + (c + 8) * 32 + kq * 8;
            const size_t base = (size_t)(kc >> 4) * 8192 + (kc & 15);
            a1[0][c] = *(const bf16x8*)(hprev + base + (size_t)br0 * 16);
            a1[1][c] = *(const bf16x8*)(hprev + base + (size_t)(br0 + 16) * 16);
        }
        __builtin_amdgcn_sched_barrier(0);

        // ---- h batch 0 MFMAs (a0 arrived during x-loop) ----
        #pragma unroll
        for (int c = 0; c < 8; ++c) {
            const int u0 = ks * 64 + c * 4 + kq;
            const int woff = ((u0 ^ (lr & 7)) << 4);
            #pragma unroll
            for (int g = 0; g < 4; ++g) {
                bf16x8 wf = *(const bf16x8*)((const char*)WhL + (g * 16 + lr) * 2048 + woff);
                acc[0][g] = __builtin_amdgcn_mfma_f32_16x16x32_bf16(a0[0][c], wf, acc[0][g], 0, 0, 0);
                acc[1][g] = __builtin_amdgcn_mfma_f32_16x16x32_bf16(a0[1][c], wf, acc[1][g], 0, 0, 0);
            }
        }
        __builtin_amdgcn_sched_barrier(0);
        asm volatile("s_waitcnt vmcnt(0)" ::: "memory");   // a1 ready
        __builtin_amdgcn_sched_barrier(0);
        #pragma unroll
        for (int c = 0; c < 8; ++c) {
            const int u0 = ks * 64 + (c + 8) * 4 + kq;
            const int woff = ((u0 ^ (lr & 7)) << 4);
            #pragma unroll
            for (int g = 0; g < 4; ++g) {
                bf16x8 wf = *(const bf16x8*)((const char*)WhL + (g * 16 + lr) * 2048 + woff);
                acc[0][g] = __builtin_amdgcn_mfma_f32_16x16x32_bf16(a1[0][c], wf, acc[0][g], 0, 0, 0);
                acc[1][g] = __builtin_amdgcn_mfma_f32_16x16x32_bf16(a1[1][c], wf, acc[1][g], 0, 0, 0);
            }
        }

        // ---- 3-barrier ks exchange ----
        if (ks == 1) {
            #pragma unroll
            for (int g = 0; g < 4; ++g)
                *(f32x4*)&WS[mg * 1024 + g * 256 + lane * 4] = acc[0][g];
        }
        __syncthreads();
        if (ks == 0) {
            #pragma unroll
            for (int g = 0; g < 4; ++g)
                accf[g] = acc[0][g] + *(const f32x4*)&WS[mg * 1024 + g * 256 + lane * 4];
        }
        __syncthreads();
        if (ks == 0) {
            #pragma unroll
            for (int g = 0; g < 4; ++g)
                *(f32x4*)&WS[mg * 1024 + g * 256 + lane * 4] = acc[1][g];
        }
        __syncthreads();
        if (ks == 1) {
            #pragma unroll
            for (int g = 0; g < 4; ++g)
                accf[g] = acc[1][g] + *(const f32x4*)&WS[mg * 1024 + g * 256 + lane * 4];
        }
    } else {
        // ---- t == 0: x-projection only (plain, compiler-scheduled) ----
        float bv[4];
        #pragma unroll
        for (int g = 0; g < 4; ++g) bv[g] = bias[g * HSZ + n];
        cr = (f32x4){0.f, 0.f, 0.f, 0.f};

        f32x4 acc[2][4];
        #pragma unroll
        for (int m = 0; m < 2; ++m)
            #pragma unroll
            for (int g = 0; g < 4; ++g)
                acc[m][g] = (ks == 0) ? (f32x4){bv[g], bv[g], bv[g], bv[g]}
                                      : (f32x4){0.f, 0.f, 0.f, 0.f};
        bf16x8 ax[2][8];
        #pragma unroll
        for (int j = 0; j < 8; ++j) {
            ax[0][j] = *(const bf16x8*)(xr + j * 32);
            ax[1][j] = *(const bf16x8*)(xr + 16 * ISZ + j * 32);
        }
        #pragma unroll
        for (int j = 0; j < 8; ++j) {
            #pragma unroll
            for (int g = 0; g < 4; ++g) {
                bf16x8 wf = *(const bf16x8*)(wih_p + (size_t)g * (HSZ * ISZ) + j * 32);
                acc[0][g] = __builtin_amdgcn_mfma_f32_16x16x32_bf16(ax[0][j], wf, acc[0][g], 0, 0, 0);
                acc[1][g] = __builtin_amdgcn_mfma_f32_16x16x32_bf16(ax[1][j], wf, acc[1][g], 0, 0, 0);
            }
        }
        // exchange (same as above; x-part is ks-split too)
        if (ks == 1) {
            #pragma unroll
            for (int g = 0; g < 4; ++g)
                *(f32x4*)&WS[mg * 1024 + g * 256 + lane * 4] = acc[0][g];
        }
        __syncthreads();
        if (ks == 0) {
            #pragma unroll
            for (int g = 0; g < 4; ++g)
                accf[g] = acc[0][g] + *(const f32x4*)&WS[mg * 1024 + g * 256 + lane * 4];
        }
        __syncthreads();
        if (ks == 0) {
            #pragma unroll
            for (int g = 0; g < 4; ++g)
                *(f32x4*)&WS[mg * 1024 + g * 256 + lane * 4] = acc[1][g];
        }
        __syncthreads();
        if (ks == 1) {
            #pragma unroll
            for (int g = 0; g < 4; ++g)
                accf[g] = acc[1][g] + *(const f32x4*)&WS[mg * 1024 + g * 256 + lane * 4];
        }
    }

    // ---- LSTM pointwise epilogue (each thread: 4 rows x 1 col) ----
    unsigned short* hslab = hnext + (size_t)ni * 8192;
    float* outt = out + (size_t)t * BSZ * HSZ;
    float* hnp = out + (size_t)TT * BSZ * HSZ;
    float* cnp = hnp + (size_t)BSZ * HSZ;
    #pragma unroll
    for (int r = 0; r < 4; ++r) {
        float gi = accf[0][r];
        float gf = accf[1][r];
        float gg = accf[2][r];
        float go = accf[3][r];
        float ig = 1.f / (1.f + __expf(-gi));
        float fg = 1.f / (1.f + __expf(-gf));
        float gv = 1.f - 2.f / (__expf(2.f * gg) + 1.f);
        float og = 1.f / (1.f + __expf(-go));
        float cnew = fg * cr[r] + ig * gv;
        float h = og * (1.f - 2.f / (__expf(2.f * cnew) + 1.f));
        cr[r] = cnew;
        const size_t idx = (size_t)(bth + r) * HSZ + n;
        hslab[(size_t)(bth + r) * 16 + lr] = f2bf(h);
        outt[idx] = h;
        if (t == TT - 1) { hnp[idx] = h; cnp[idx] = cnew; }
    }
    *(f32x4*)cth = cr;
}

extern "C" void kernel_launch(void* const* d_in, const int* in_sizes, int n_in,
                              void* d_out, int out_size, void* d_ws, size_t ws_size,
                              hipStream_t stream) {
    const float* input_ = (const float*)d_in[0];
    const float* Wih = (const float*)d_in[3];
    const float* Whh = (const float*)d_in[4];
    const float* bih = (const float*)d_in[5];
    const float* bhh = (const float*)d_in[6];

    char* ws = (char*)d_ws;
    unsigned short* Wihb = (unsigned short*)(ws);                  //  4 MB
    unsigned short* Whhb = (unsigned short*)(ws + (4u << 20));     //  8 MB
    unsigned short* xb   = (unsigned short*)(ws + (12u << 20));    // 32 MB
    float*          bias = (float*)(ws + (44u << 20));             // 16 KB
    unsigned short* hb0  = (unsigned short*)(ws + (45u << 20));    //  1 MB
    unsigned short* hb1  = (unsigned short*)(ws + (46u << 20));    //  1 MB
    float*          cst  = (float*)(ws + (47u << 20));             //  2 MB

    cast_f32_to_bf16<<<1024, 256, 0, stream>>>(Wih, Wihb, (4 * HSZ * ISZ) / 8);
    cast_f32_to_bf16<<<2048, 256, 0, stream>>>(Whh, Whhb, (4 * HSZ * HSZ) / 8);
    cast_f32_to_bf16<<<8192, 256, 0, stream>>>(input_, xb, (TT * BSZ * ISZ) / 8);
    bias_combine<<<16, 256, 0, stream>>>(bih, bhh, bias);

    float* out = (float*)d_out;
    for (int t = 0; t < TT; ++t) {
        const unsigned short* hp = (t & 1) ? hb0 : hb1;
        unsigned short* hx = (t & 1) ? hb1 : hb0;
        lstm_step<<<256, 512, 0, stream>>>(xb, Wihb, Whhb, bias, hp, hx, cst, out, t);
    }
}

// Round 18
// 951.301 us; speedup vs baseline: 1.4028x; 1.4028x over previous
//
#include <hip/hip_runtime.h>

#define TT  64
#define BSZ 512
#define ISZ 512
#define HSZ 1024

typedef short bf16x8 __attribute__((ext_vector_type(8)));
typedef float f32x4 __attribute__((ext_vector_type(4)));
typedef unsigned short u16x8 __attribute__((ext_vector_type(8)));

typedef const __attribute__((address_space(1))) unsigned int* gas_t;
typedef __attribute__((address_space(3))) unsigned int* las_t;

__device__ __forceinline__ unsigned short f2bf(float f) {
    unsigned int u = __float_as_uint(f);
    unsigned int r = u + 0x7FFFu + ((u >> 16) & 1u);   // RNE
    return (unsigned short)(r >> 16);
}
__device__ __forceinline__ float bf2f(unsigned short u) {
    return __uint_as_float(((unsigned int)u) << 16);
}

__global__ void cast_f32_to_bf16(const float* __restrict__ in,
                                 unsigned short* __restrict__ out, int n8) {
    int i = blockIdx.x * blockDim.x + threadIdx.x;
    if (i >= n8) return;
    const float4* p = (const float4*)(in + (size_t)i * 8);
    float4 v0 = p[0], v1 = p[1];
    u16x8 o;
    o[0] = f2bf(v0.x); o[1] = f2bf(v0.y); o[2] = f2bf(v0.z); o[3] = f2bf(v0.w);
    o[4] = f2bf(v1.x); o[5] = f2bf(v1.y); o[6] = f2bf(v1.z); o[7] = f2bf(v1.w);
    *(u16x8*)(out + (size_t)i * 8) = o;
}

__global__ void bias_combine(const float* __restrict__ a,
                             const float* __restrict__ b,
                             float* __restrict__ o) {
    int i = blockIdx.x * blockDim.x + threadIdx.x;
    if (i < 4 * HSZ) o[i] = a[i] + b[i];
}

// ---------------- Phase 1: XG[t] = x_t @ Wih^T + bias, bf16 -----------------
// Consumer layout: [t][mi(4)][ni(64)][tid(512)][16(g*4+r)], tid mapping for
// the full-K wave decomposition: wv = row>>4, kq = (row>>2)&3, lr = col&15.
__global__ __launch_bounds__(256) void xg_gemm(
    const unsigned short* __restrict__ xb,    // [TT,512,512] bf16
    const unsigned short* __restrict__ Wihb,  // [4096,512] bf16
    const float* __restrict__ bias,           // [4096]
    unsigned short* __restrict__ XG)
{
    __shared__ unsigned short Ab[2][128 * 64];
    __shared__ unsigned short Wb[2][128 * 64];

    const int t   = blockIdx.x >> 7;
    const int j   = blockIdx.x & 127;
    const int xcd = j & 7;
    const int idx = j >> 3;
    const int hh0 = (xcd * 4 + (idx & 3)) * 32;
    const int bb0 = (idx >> 2) * 128;

    const unsigned short* A = xb + (size_t)t * BSZ * ISZ;

    const int lane = threadIdx.x & 63;
    const int wv   = threadIdx.x >> 6;
    const int wx   = wv & 1;
    const int wy   = wv >> 1;
    const int lr   = lane & 15;
    const int kq   = lane >> 4;

    const f32x4 z = {0.f, 0.f, 0.f, 0.f};
    f32x4 acc[4][4];
    #pragma unroll
    for (int m = 0; m < 4; ++m)
        #pragma unroll
        for (int g = 0; g < 4; ++g) acc[m][g] = z;

    auto stage = [&](int k0, unsigned short* Abuf, unsigned short* Wbuf) {
        const int sub = lane >> 3;
        const int swk = ((lane & 7) ^ sub) * 8;
        #pragma unroll
        for (int i = 0; i < 4; ++i) {
            const int tr8 = (wv * 4 + i) * 8;
            const unsigned short* g = A + (size_t)(bb0 + tr8 + sub) * ISZ + k0 + swk;
            __builtin_amdgcn_global_load_lds((gas_t)g, (las_t)(Abuf + tr8 * 64), 16, 0, 0);
        }
        #pragma unroll
        for (int i = 0; i < 4; ++i) {
            const int tr8 = (wv * 4 + i) * 8;
            const int tr = tr8 + sub;
            const int wrow = hh0 + (tr & 31) + (tr >> 5) * 1024;
            const unsigned short* g = Wihb + (size_t)wrow * ISZ + k0 + swk;
            __builtin_amdgcn_global_load_lds((gas_t)g, (las_t)(Wbuf + tr8 * 64), 16, 0, 0);
        }
    };

    stage(0, Ab[0], Wb[0]);
    const int swz = (lr & 7) << 4;
    for (int c = 0; c < 8; ++c) {
        const int buf = c & 1;
        if (c + 1 < 8) {
            stage((c + 1) * 64, Ab[buf ^ 1], Wb[buf ^ 1]);
            asm volatile("s_waitcnt vmcnt(8)" ::: "memory");
        } else {
            asm volatile("s_waitcnt vmcnt(0)" ::: "memory");
        }
        __builtin_amdgcn_sched_barrier(0);
        __builtin_amdgcn_s_barrier();

        const char* Ac = (const char*)Ab[buf];
        const char* Wc = (const char*)Wb[buf];
        #pragma unroll
        for (int ks = 0; ks < 2; ++ks) {
            const int kb = ks * 64 + kq * 16;
            bf16x8 wf[4], af[4];
            #pragma unroll
            for (int g = 0; g < 4; ++g) {
                const int tr = g * 32 + wx * 16 + lr;
                wf[g] = *(const bf16x8*)(Wc + tr * 128 + (kb ^ swz));
            }
            #pragma unroll
            for (int m = 0; m < 4; ++m) {
                const int tr = wy * 64 + m * 16 + lr;
                af[m] = *(const bf16x8*)(Ac + tr * 128 + (kb ^ swz));
            }
            #pragma unroll
            for (int m = 0; m < 4; ++m)
                #pragma unroll
                for (int g = 0; g < 4; ++g)
                    acc[m][g] = __builtin_amdgcn_mfma_f32_16x16x32_bf16(af[m], wf[g], acc[m][g], 0, 0, 0);
        }
        __builtin_amdgcn_s_barrier();
    }

    // ---- epilogue: scatter into consumer layout (full-K wave mapping) ----
    const int n = hh0 + wx * 16 + lr;
    float bv[4];
    #pragma unroll
    for (int g = 0; g < 4; ++g) bv[g] = bias[g * HSZ + n];
    unsigned short* XGt = XG + (size_t)t * (4 * 64 * 8192);
    const size_t slab = ((size_t)(bb0 >> 7) * 64 + (n >> 4)) * 8192;
    #pragma unroll
    for (int m = 0; m < 4; ++m) {
        const int tid_c = (wy * 4 + m) * 64 + kq * 16 + lr;
        u16x8 o0, o1;
        #pragma unroll
        for (int g = 0; g < 4; ++g)
            #pragma unroll
            for (int r = 0; r < 4; ++r) {
                const unsigned short v = f2bf(acc[m][g][r] + bv[g]);
                if (g < 2) o0[g * 4 + r] = v;
                else       o1[(g - 2) * 4 + r] = v;
            }
        *(u16x8*)(XGt + slab + (size_t)tid_c * 16) = o0;
        *(u16x8*)(XGt + slab + (size_t)tid_c * 16 + 8) = o1;
    }
}

// ---------------- Phase 2: one launch per step, FULL-K waves ----------------
// 256 blocks (1/CU via 128KB LDS), 512 thr = 8 waves. mi=bid>>6, ni=bid&63.
// Wave wv owns rows [b0+wv*16, +16), full K=1024, 16 cols x 4 gates ->
// accumulator complete per wave: NO ks-exchange, NO WS, 3 fewer barriers.
// W_hh slice staged to LDS each launch (L2-warm), pinned issue order:
// W(16) | a0(16) | a1(16) | xg+c(3) -> vmcnt(35), barrier -> vmcnt(19) ->
// MFMA c0..15 -> vmcnt(3) -> MFMA c16..31 -> fused epilogue.
__global__ __launch_bounds__(512, 2) void lstm_step(
    const unsigned short* __restrict__ XG,    // [TT][4][64][512][16] bf16
    const unsigned short* __restrict__ Whhb,  // [4096,1024] bf16
    const unsigned short* __restrict__ hprev, // [64][512][16] bf16
    unsigned short* __restrict__ hnext,       // [64][512][16] bf16
    float* __restrict__ cst,                  // [4*64*512][4] fp32
    float* __restrict__ out,
    int t)
{
    __shared__ unsigned short WhL[64 * 1024];   // 128 KiB W_hh slice

    const int tid  = threadIdx.x;
    const int lane = tid & 63;
    const int wv   = tid >> 6;       // 0..7 = 16-row group, full K
    const int lr   = lane & 15;
    const int kq   = lane >> 4;
    const int mi   = blockIdx.x >> 6;
    const int ni   = blockIdx.x & 63;
    const int b0   = mi * 128;
    const int hc0  = ni * 16;

    const int bth = b0 + wv * 16 + kq * 4;     // this thread's 4 rows
    const int n   = hc0 + lr;
    const unsigned short* xgt = XG + (size_t)t * 2097152
                              + ((size_t)mi * 64 + ni) * 8192 + (size_t)tid * 16;
    float* cth = cst + (((size_t)mi * 64 + ni) * 512 + tid) * 4;

    f32x4 acc[4];
    #pragma unroll
    for (int g = 0; g < 4; ++g) acc[g] = (f32x4){0.f, 0.f, 0.f, 0.f};
    f32x4 cr;
    bf16x8 xg0, xg1;

    if (t > 0) {
        // ---- group 1: W_hh stage (16 gload_lds) ----
        #pragma unroll
        for (int i = 0; i < 16; ++i) {
            const int li = wv * 16 + i;
            const int r = li >> 1, half = li & 1;
            const int grow = (r >> 4) * HSZ + hc0 + (r & 15);
            const int gslot = (half * 64 + lane) ^ (r & 7);
            const unsigned short* g = Whhb + (size_t)grow * HSZ + (size_t)gslot * 8;
            __builtin_amdgcn_global_load_lds((gas_t)g, (las_t)(WhL + li * 512), 16, 0, 0);
        }
        __builtin_amdgcn_sched_barrier(0);

        // ---- group 2: h batch 0 (16 loads, k = 0..511) ----
        const int br0 = b0 + wv * 16 + lr;
        bf16x8 a0[16], a1[16];
        #pragma unroll
        for (int c = 0; c < 16; ++c) {
            const int kc = c * 32 + kq * 8;
            const size_t base = (size_t)(kc >> 4) * 8192 + (kc & 15);
            a0[c] = *(const bf16x8*)(hprev + base + (size_t)br0 * 16);
        }
        __builtin_amdgcn_sched_barrier(0);
        // ---- group 3: h batch 1 (16 loads, k = 512..1023) ----
        #pragma unroll
        for (int c = 0; c < 16; ++c) {
            const int kc = (c + 16) * 32 + kq * 8;
            const size_t base = (size_t)(kc >> 4) * 8192 + (kc & 15);
            a1[c] = *(const bf16x8*)(hprev + base + (size_t)br0 * 16);
        }
        __builtin_amdgcn_sched_barrier(0);

        // ---- group 4: xg + c (3 loads) ----
        xg0 = *(const bf16x8*)(xgt);
        xg1 = *(const bf16x8*)(xgt + 8);
        cr  = *(const f32x4*)(cth);
        __builtin_amdgcn_sched_barrier(0);

        // ---- own W writes done (younger: a0 16 + a1 16 + xg/c 3 = 35) ----
        asm volatile("s_waitcnt vmcnt(35)" ::: "memory");
        __builtin_amdgcn_sched_barrier(0);
        __builtin_amdgcn_s_barrier();       // all waves' W writes visible

        // ---- batch 0 ready (younger: a1 16 + xg/c 3 = 19) ----
        asm volatile("s_waitcnt vmcnt(19)" ::: "memory");
        __builtin_amdgcn_sched_barrier(0);
        #pragma unroll
        for (int c = 0; c < 16; ++c) {
            const int u0 = c * 4 + kq;
            const int woff = ((u0 ^ (lr & 7)) << 4);
            #pragma unroll
            for (int g = 0; g < 4; ++g) {
                bf16x8 wf = *(const bf16x8*)((const char*)WhL + (g * 16 + lr) * 2048 + woff);
                acc[g] = __builtin_amdgcn_mfma_f32_16x16x32_bf16(a0[c], wf, acc[g], 0, 0, 0);
            }
        }
        __builtin_amdgcn_sched_barrier(0);
        // ---- batch 1 ready (younger: xg/c 3) ----
        asm volatile("s_waitcnt vmcnt(3)" ::: "memory");
        __builtin_amdgcn_sched_barrier(0);
        #pragma unroll
        for (int c = 0; c < 16; ++c) {
            const int u0 = (c + 16) * 4 + kq;
            const int woff = ((u0 ^ (lr & 7)) << 4);
            #pragma unroll
            for (int g = 0; g < 4; ++g) {
                bf16x8 wf = *(const bf16x8*)((const char*)WhL + (g * 16 + lr) * 2048 + woff);
                acc[g] = __builtin_amdgcn_mfma_f32_16x16x32_bf16(a1[c], wf, acc[g], 0, 0, 0);
            }
        }
    } else {
        xg0 = *(const bf16x8*)(xgt);
        xg1 = *(const bf16x8*)(xgt + 8);
        cr  = (f32x4){0.f, 0.f, 0.f, 0.f};
    }

    // ---- fused LSTM pointwise epilogue (each thread: 4 rows x 1 col) ----
    unsigned short* hslab = hnext + (size_t)ni * 8192;
    float* outt = out + (size_t)t * BSZ * HSZ;
    float* hnp = out + (size_t)TT * BSZ * HSZ;
    float* cnp = hnp + (size_t)BSZ * HSZ;
    #pragma unroll
    for (int r = 0; r < 4; ++r) {
        float gi = acc[0][r] + bf2f((unsigned short)xg0[r]);
        float gf = acc[1][r] + bf2f((unsigned short)xg0[4 + r]);
        float gg = acc[2][r] + bf2f((unsigned short)xg1[r]);
        float go = acc[3][r] + bf2f((unsigned short)xg1[4 + r]);
        float ig = 1.f / (1.f + __expf(-gi));
        float fg = 1.f / (1.f + __expf(-gf));
        float gv = 1.f - 2.f / (__expf(2.f * gg) + 1.f);
        float og = 1.f / (1.f + __expf(-go));
        float cnew = fg * cr[r] + ig * gv;
        float h = og * (1.f - 2.f / (__expf(2.f * cnew) + 1.f));
        cr[r] = cnew;
        const size_t idx = (size_t)(bth + r) * HSZ + n;
        hslab[(size_t)(bth + r) * 16 + lr] = f2bf(h);
        outt[idx] = h;
        if (t == TT - 1) { hnp[idx] = h; cnp[idx] = cnew; }
    }
    *(f32x4*)cth = cr;
}

extern "C" void kernel_launch(void* const* d_in, const int* in_sizes, int n_in,
                              void* d_out, int out_size, void* d_ws, size_t ws_size,
                              hipStream_t stream) {
    const float* input_ = (const float*)d_in[0];
    const float* Wih = (const float*)d_in[3];
    const float* Whh = (const float*)d_in[4];
    const float* bih = (const float*)d_in[5];
    const float* bhh = (const float*)d_in[6];

    char* ws = (char*)d_ws;
    unsigned short* Wihb = (unsigned short*)(ws);                  //   4 MB
    unsigned short* Whhb = (unsigned short*)(ws + (4u << 20));     //   8 MB
    unsigned short* xb   = (unsigned short*)(ws + (12u << 20));    //  32 MB
    float*          bias = (float*)(ws + (44u << 20));             //  16 KB
    unsigned short* hb0  = (unsigned short*)(ws + (45u << 20));    //   1 MB
    unsigned short* hb1  = (unsigned short*)(ws + (46u << 20));    //   1 MB
    float*          cst  = (float*)(ws + (47u << 20));             //   2 MB
    unsigned short* XG   = (unsigned short*)(ws + (50u << 20));    // 256 MB

    cast_f32_to_bf16<<<1024, 256, 0, stream>>>(Wih, Wihb, (4 * HSZ * ISZ) / 8);
    cast_f32_to_bf16<<<2048, 256, 0, stream>>>(Whh, Whhb, (4 * HSZ * HSZ) / 8);
    cast_f32_to_bf16<<<8192, 256, 0, stream>>>(input_, xb, (TT * BSZ * ISZ) / 8);
    bias_combine<<<16, 256, 0, stream>>>(bih, bhh, bias);

    float* out = (float*)d_out;
    xg_gemm<<<TT * 128, 256, 0, stream>>>(xb, Wihb, bias, XG);
    for (int t = 0; t < TT; ++t) {
        const unsigned short* hp = (t & 1) ? hb0 : hb1;
        unsigned short* hx = (t & 1) ? hb1 : hb0;
        lstm_step<<<256, 512, 0, stream>>>(XG, Whhb, hp, hx, cst, out, t);
    }
}

// Round 19
// 914.399 us; speedup vs baseline: 1.4594x; 1.0404x over previous
//
#include <hip/hip_runtime.h>

#define TT  64
#define BSZ 512
#define ISZ 512
#define HSZ 1024

typedef short bf16x8 __attribute__((ext_vector_type(8)));
typedef float f32x4 __attribute__((ext_vector_type(4)));
typedef unsigned short u16x8 __attribute__((ext_vector_type(8)));

typedef const __attribute__((address_space(1))) unsigned int* gas_t;
typedef __attribute__((address_space(3))) unsigned int* las_t;

__device__ __forceinline__ unsigned short f2bf(float f) {
    unsigned int u = __float_as_uint(f);
    unsigned int r = u + 0x7FFFu + ((u >> 16) & 1u);   // RNE
    return (unsigned short)(r >> 16);
}
__device__ __forceinline__ float bf2f(unsigned short u) {
    return __uint_as_float(((unsigned int)u) << 16);
}

// ---- fused prep: all three bf16 casts + bias combine in one launch ----
__global__ void prep_all(const float* __restrict__ Wih,
                         const float* __restrict__ Whh,
                         const float* __restrict__ x,
                         const float* __restrict__ bih,
                         const float* __restrict__ bhh,
                         unsigned short* __restrict__ Wihb,
                         unsigned short* __restrict__ Whhb,
                         unsigned short* __restrict__ xbo,
                         float* __restrict__ bias) {
    const int i0 = blockIdx.x * blockDim.x + threadIdx.x;
    const int stride = gridDim.x * blockDim.x;
    if (i0 < 4 * HSZ) bias[i0] = bih[i0] + bhh[i0];
    const int n1 = (4 * HSZ * ISZ) / 8;             // Wih groups
    const int n2 = n1 + (4 * HSZ * HSZ) / 8;        // + Whh groups
    const int n3 = n2 + (TT * BSZ * ISZ) / 8;       // + x groups
    for (int k = i0; k < n3; k += stride) {
        const float* src; unsigned short* dst; int off;
        if (k < n1)      { src = Wih; dst = Wihb; off = k; }
        else if (k < n2) { src = Whh; dst = Whhb; off = k - n1; }
        else             { src = x;   dst = xbo;  off = k - n2; }
        const float4* p = (const float4*)(src + (size_t)off * 8);
        float4 v0 = p[0], v1 = p[1];
        u16x8 o;
        o[0] = f2bf(v0.x); o[1] = f2bf(v0.y); o[2] = f2bf(v0.z); o[3] = f2bf(v0.w);
        o[4] = f2bf(v1.x); o[5] = f2bf(v1.y); o[6] = f2bf(v1.z); o[7] = f2bf(v1.w);
        *(u16x8*)(dst + (size_t)off * 8) = o;
    }
}

// ---------------- Phase 1: XG[t] = x_t @ Wih^T + bias, bf16 -----------------
// Consumer layout: [t][mi(4)][ni(64)][tid(512)][16(g*4+r)] for the ks-split
// step decomposition (tid = (ks*4+mg)*64 + kq*16 + lr).
__global__ __launch_bounds__(256, 2) void xg_gemm(
    const unsigned short* __restrict__ xb,    // [TT,512,512] bf16
    const unsigned short* __restrict__ Wihb,  // [4096,512] bf16
    const float* __restrict__ bias,           // [4096]
    unsigned short* __restrict__ XG)
{
    __shared__ unsigned short Ab[2][128 * 64];
    __shared__ unsigned short Wb[2][128 * 64];

    const int t   = blockIdx.x >> 7;
    const int j   = blockIdx.x & 127;
    const int xcd = j & 7;
    const int idx = j >> 3;
    const int hh0 = (xcd * 4 + (idx & 3)) * 32;
    const int bb0 = (idx >> 2) * 128;

    const unsigned short* A = xb + (size_t)t * BSZ * ISZ;

    const int lane = threadIdx.x & 63;
    const int wv   = threadIdx.x >> 6;
    const int wx   = wv & 1;
    const int wy   = wv >> 1;
    const int lr   = lane & 15;
    const int kq   = lane >> 4;

    const f32x4 z = {0.f, 0.f, 0.f, 0.f};
    f32x4 acc[4][4];
    #pragma unroll
    for (int m = 0; m < 4; ++m)
        #pragma unroll
        for (int g = 0; g < 4; ++g) acc[m][g] = z;

    auto stage = [&](int k0, unsigned short* Abuf, unsigned short* Wbuf) {
        const int sub = lane >> 3;
        const int swk = ((lane & 7) ^ sub) * 8;
        #pragma unroll
        for (int i = 0; i < 4; ++i) {
            const int tr8 = (wv * 4 + i) * 8;
            const unsigned short* g = A + (size_t)(bb0 + tr8 + sub) * ISZ + k0 + swk;
            __builtin_amdgcn_global_load_lds((gas_t)g, (las_t)(Abuf + tr8 * 64), 16, 0, 0);
        }
        #pragma unroll
        for (int i = 0; i < 4; ++i) {
            const int tr8 = (wv * 4 + i) * 8;
            const int tr = tr8 + sub;
            const int wrow = hh0 + (tr & 31) + (tr >> 5) * 1024;
            const unsigned short* g = Wihb + (size_t)wrow * ISZ + k0 + swk;
            __builtin_amdgcn_global_load_lds((gas_t)g, (las_t)(Wbuf + tr8 * 64), 16, 0, 0);
        }
    };

    stage(0, Ab[0], Wb[0]);
    const int swz = (lr & 7) << 4;
    for (int c = 0; c < 8; ++c) {
        const int buf = c & 1;
        if (c + 1 < 8) {
            stage((c + 1) * 64, Ab[buf ^ 1], Wb[buf ^ 1]);
            asm volatile("s_waitcnt vmcnt(8)" ::: "memory");
        } else {
            asm volatile("s_waitcnt vmcnt(0)" ::: "memory");
        }
        __builtin_amdgcn_sched_barrier(0);
        __builtin_amdgcn_s_barrier();

        const char* Ac = (const char*)Ab[buf];
        const char* Wc = (const char*)Wb[buf];
        #pragma unroll
        for (int ks = 0; ks < 2; ++ks) {
            const int kb = ks * 64 + kq * 16;
            bf16x8 wf[4], af[4];
            #pragma unroll
            for (int g = 0; g < 4; ++g) {
                const int tr = g * 32 + wx * 16 + lr;
                wf[g] = *(const bf16x8*)(Wc + tr * 128 + (kb ^ swz));
            }
            #pragma unroll
            for (int m = 0; m < 4; ++m) {
                const int tr = wy * 64 + m * 16 + lr;
                af[m] = *(const bf16x8*)(Ac + tr * 128 + (kb ^ swz));
            }
            #pragma unroll
            for (int m = 0; m < 4; ++m)
                #pragma unroll
                for (int g = 0; g < 4; ++g)
                    acc[m][g] = __builtin_amdgcn_mfma_f32_16x16x32_bf16(af[m], wf[g], acc[m][g], 0, 0, 0);
        }
        __builtin_amdgcn_s_barrier();
    }

    // ---- epilogue: scatter into consumer layout (ks-split mapping) ----
    const int n = hh0 + wx * 16 + lr;
    float bv[4];
    #pragma unroll
    for (int g = 0; g < 4; ++g) bv[g] = bias[g * HSZ + n];
    unsigned short* XGt = XG + (size_t)t * (4 * 64 * 8192);
    const size_t slab = ((size_t)(bb0 >> 7) * 64 + (n >> 4)) * 8192;
    #pragma unroll
    for (int m = 0; m < 4; ++m) {
        const int tid_c = ((m & 1) * 4 + wy * 2 + (m >> 1)) * 64 + kq * 16 + lr;
        u16x8 o0, o1;
        #pragma unroll
        for (int g = 0; g < 4; ++g)
            #pragma unroll
            for (int r = 0; r < 4; ++r) {
                const unsigned short v = f2bf(acc[m][g][r] + bv[g]);
                if (g < 2) o0[g * 4 + r] = v;
                else       o1[(g - 2) * 4 + r] = v;
            }
        *(u16x8*)(XGt + slab + (size_t)tid_c * 16) = o0;
        *(u16x8*)(XGt + slab + (size_t)tid_c * 16 + 8) = o1;
    }
}

// ---------------- Phase 2: one launch per step (R15 proven structure) -------
// 256 blocks (1/CU via 144KB LDS), 512 thr = 8 waves. mi=bid>>6, ni=bid&63.
// Wave (mg = wv&3: 32 rows, ks = wv>>2: K-half). W_hh slice LDS-resident per
// launch; pinned issue order W(16) | a0(16) | a1(16) | xg+c(3) with counted
// vmcnt 35/19/3; 3-barrier ks exchange; fused LSTM epilogue.
__global__ __launch_bounds__(512, 2) void lstm_step(
    const unsigned short* __restrict__ XG,    // [TT][4][64][512][16] bf16
    const unsigned short* __restrict__ Whhb,  // [4096,1024] bf16
    const unsigned short* __restrict__ hprev, // [64][512][16] bf16
    unsigned short* __restrict__ hnext,       // [64][512][16] bf16
    float* __restrict__ cst,                  // [4*64*512][4] fp32
    float* __restrict__ out,
    int t)
{
    __shared__ unsigned short WhL[64 * 1024];   // 128 KiB W_hh slice
    __shared__ float WS[4096];                  //  16 KiB ks exchange

    const int tid  = threadIdx.x;
    const int lane = tid & 63;
    const int wv   = tid >> 6;
    const int mg   = wv & 3;
    const int ks   = wv >> 2;
    const int lr   = lane & 15;
    const int kq   = lane >> 4;
    const int mi   = blockIdx.x >> 6;
    const int ni   = blockIdx.x & 63;
    const int b0   = mi * 128;
    const int hc0  = ni * 16;

    const int bth = b0 + mg * 32 + ks * 16 + kq * 4;   // this thread's 4 rows
    const int n   = hc0 + lr;
    const unsigned short* xgt = XG + (size_t)t * 2097152
                              + ((size_t)mi * 64 + ni) * 8192 + (size_t)tid * 16;
    float* cth = cst + (((size_t)mi * 64 + ni) * 512 + tid) * 4;

    f32x4 accf[4];
    f32x4 cr;
    bf16x8 xg0, xg1;

    if (t > 0) {
        // ---- group 1: W_hh stage (16 gload_lds) ----
        #pragma unroll
        for (int i = 0; i < 16; ++i) {
            const int li = wv * 16 + i;
            const int r = li >> 1, half = li & 1;
            const int grow = (r >> 4) * HSZ + hc0 + (r & 15);
            const int gslot = (half * 64 + lane) ^ (r & 7);
            const unsigned short* g = Whhb + (size_t)grow * HSZ + (size_t)gslot * 8;
            __builtin_amdgcn_global_load_lds((gas_t)g, (las_t)(WhL + li * 512), 16, 0, 0);
        }
        __builtin_amdgcn_sched_barrier(0);

        // ---- group 2: h batch 0 (16 loads) ----
        const int br0 = b0 + mg * 32 + lr;
        bf16x8 a0[2][8], a1[2][8];
        #pragma unroll
        for (int c = 0; c < 8; ++c) {
            const int kc = ks * 512 + c * 32 + kq * 8;
            const size_t base = (size_t)(kc >> 4) * 8192 + (kc & 15);
            a0[0][c] = *(const bf16x8*)(hprev + base + (size_t)br0 * 16);
            a0[1][c] = *(const bf16x8*)(hprev + base + (size_t)(br0 + 16) * 16);
        }
        __builtin_amdgcn_sched_barrier(0);
        // ---- group 3: h batch 1 (16 loads) ----
        #pragma unroll
        for (int c = 0; c < 8; ++c) {
            const int kc = ks * 512 + (c + 8) * 32 + kq * 8;
            const size_t base = (size_t)(kc >> 4) * 8192 + (kc & 15);
            a1[0][c] = *(const bf16x8*)(hprev + base + (size_t)br0 * 16);
            a1[1][c] = *(const bf16x8*)(hprev + base + (size_t)(br0 + 16) * 16);
        }
        __builtin_amdgcn_sched_barrier(0);

        // ---- group 4: xg + c (3 loads) ----
        xg0 = *(const bf16x8*)(xgt);
        xg1 = *(const bf16x8*)(xgt + 8);
        cr  = *(const f32x4*)(cth);
        __builtin_amdgcn_sched_barrier(0);

        // ---- own W writes done (younger: a0 16 + a1 16 + xg/c 3 = 35) ----
        asm volatile("s_waitcnt vmcnt(35)" ::: "memory");
        __builtin_amdgcn_sched_barrier(0);
        __builtin_amdgcn_s_barrier();       // all waves' W writes visible

        const f32x4 z = {0.f, 0.f, 0.f, 0.f};
        f32x4 acc[2][4];
        #pragma unroll
        for (int m = 0; m < 2; ++m)
            #pragma unroll
            for (int g = 0; g < 4; ++g) acc[m][g] = z;

        // ---- batch 0 ready (younger: a1 16 + xg/c 3 = 19) ----
        asm volatile("s_waitcnt vmcnt(19)" ::: "memory");
        __builtin_amdgcn_sched_barrier(0);
        #pragma unroll
        for (int c = 0; c < 8; ++c) {
            const int u0 = ks * 64 + c * 4 + kq;
            const int woff = ((u0 ^ (lr & 7)) << 4);
            #pragma unroll
            for (int g = 0; g < 4; ++g) {
                bf16x8 wf = *(const bf16x8*)((const char*)WhL + (g * 16 + lr) * 2048 + woff);
                acc[0][g] = __builtin_amdgcn_mfma_f32_16x16x32_bf16(a0[0][c], wf, acc[0][g], 0, 0, 0);
                acc[1][g] = __builtin_amdgcn_mfma_f32_16x16x32_bf16(a0[1][c], wf, acc[1][g], 0, 0, 0);
            }
        }
        __builtin_amdgcn_sched_barrier(0);
        // ---- batch 1 ready (younger: xg/c 3) ----
        asm volatile("s_waitcnt vmcnt(3)" ::: "memory");
        __builtin_amdgcn_sched_barrier(0);
        #pragma unroll
        for (int c = 0; c < 8; ++c) {
            const int u0 = ks * 64 + (c + 8) * 4 + kq;
            const int woff = ((u0 ^ (lr & 7)) << 4);
            #pragma unroll
            for (int g = 0; g < 4; ++g) {
                bf16x8 wf = *(const bf16x8*)((const char*)WhL + (g * 16 + lr) * 2048 + woff);
                acc[0][g] = __builtin_amdgcn_mfma_f32_16x16x32_bf16(a1[0][c], wf, acc[0][g], 0, 0, 0);
                acc[1][g] = __builtin_amdgcn_mfma_f32_16x16x32_bf16(a1[1][c], wf, acc[1][g], 0, 0, 0);
            }
        }

        // ---- 3-barrier ks exchange ----
        if (ks == 1) {
            #pragma unroll
            for (int g = 0; g < 4; ++g)
                *(f32x4*)&WS[mg * 1024 + g * 256 + lane * 4] = acc[0][g];
        }
        __syncthreads();
        if (ks == 0) {
            #pragma unroll
            for (int g = 0; g < 4; ++g)
                accf[g] = acc[0][g] + *(const f32x4*)&WS[mg * 1024 + g * 256 + lane * 4];
        }
        __syncthreads();
        if (ks == 0) {
            #pragma unroll
            for (int g = 0; g < 4; ++g)
                *(f32x4*)&WS[mg * 1024 + g * 256 + lane * 4] = acc[1][g];
        }
        __syncthreads();
        if (ks == 1) {
            #pragma unroll
            for (int g = 0; g < 4; ++g)
                accf[g] = acc[1][g] + *(const f32x4*)&WS[mg * 1024 + g * 256 + lane * 4];
        }
    } else {
        xg0 = *(const bf16x8*)(xgt);
        xg1 = *(const bf16x8*)(xgt + 8);
        cr  = (f32x4){0.f, 0.f, 0.f, 0.f};
        #pragma unroll
        for (int g = 0; g < 4; ++g) accf[g] = (f32x4){0.f, 0.f, 0.f, 0.f};
    }

    // ---- LSTM pointwise epilogue (each thread: 4 rows x 1 col) ----
    unsigned short* hslab = hnext + (size_t)ni * 8192;
    float* outt = out + (size_t)t * BSZ * HSZ;
    float* hnp = out + (size_t)TT * BSZ * HSZ;
    float* cnp = hnp + (size_t)BSZ * HSZ;
    #pragma unroll
    for (int r = 0; r < 4; ++r) {
        float gi = accf[0][r] + bf2f((unsigned short)xg0[r]);
        float gf = accf[1][r] + bf2f((unsigned short)xg0[4 + r]);
        float gg = accf[2][r] + bf2f((unsigned short)xg1[r]);
        float go = accf[3][r] + bf2f((unsigned short)xg1[4 + r]);
        float ig = 1.f / (1.f + __expf(-gi));
        float fg = 1.f / (1.f + __expf(-gf));
        float gv = 1.f - 2.f / (__expf(2.f * gg) + 1.f);
        float og = 1.f / (1.f + __expf(-go));
        float cnew = fg * cr[r] + ig * gv;
        float h = og * (1.f - 2.f / (__expf(2.f * cnew) + 1.f));
        cr[r] = cnew;
        const size_t idx = (size_t)(bth + r) * HSZ + n;
        hslab[(size_t)(bth + r) * 16 + lr] = f2bf(h);
        outt[idx] = h;
        if (t == TT - 1) { hnp[idx] = h; cnp[idx] = cnew; }
    }
    *(f32x4*)cth = cr;
}

extern "C" void kernel_launch(void* const* d_in, const int* in_sizes, int n_in,
                              void* d_out, int out_size, void* d_ws, size_t ws_size,
                              hipStream_t stream) {
    const float* input_ = (const float*)d_in[0];
    const float* Wih = (const float*)d_in[3];
    const float* Whh = (const float*)d_in[4];
    const float* bih = (const float*)d_in[5];
    const float* bhh = (const float*)d_in[6];

    char* ws = (char*)d_ws;
    unsigned short* Wihb = (unsigned short*)(ws);                  //   4 MB
    unsigned short* Whhb = (unsigned short*)(ws + (4u << 20));     //   8 MB
    unsigned short* xb   = (unsigned short*)(ws + (12u << 20));    //  32 MB
    float*          bias = (float*)(ws + (44u << 20));             //  16 KB
    unsigned short* hb0  = (unsigned short*)(ws + (45u << 20));    //   1 MB
    unsigned short* hb1  = (unsigned short*)(ws + (46u << 20));    //   1 MB
    float*          cst  = (float*)(ws + (47u << 20));             //   2 MB
    unsigned short* XG   = (unsigned short*)(ws + (50u << 20));    // 256 MB

    prep_all<<<2048, 256, 0, stream>>>(Wih, Whh, input_, bih, bhh,
                                       Wihb, Whhb, xb, bias);

    float* out = (float*)d_out;
    xg_gemm<<<TT * 128, 256, 0, stream>>>(xb, Wihb, bias, XG);
    for (int t = 0; t < TT; ++t) {
        const unsigned short* hp = (t & 1) ? hb0 : hb1;
        unsigned short* hx = (t & 1) ? hb1 : hb0;
        lstm_step<<<256, 512, 0, stream>>>(XG, Whhb, hp, hx, cst, out, t);
    }
}